// Round 1
// baseline (5642.712 us; speedup 1.0000x reference)
//
#include <hip/hip_runtime.h>

#define N_NODES 100000
#define N_EDGES 50000
#define NNZ     800000
#define D       256

#define ROWS_PER_BLOCK 8

// ---------------------------------------------------------------------------
// Kernel 1: Xp = X @ W   (f32, LDS-staged rows, thread-per-column)
// ---------------------------------------------------------------------------
__global__ __launch_bounds__(256) void gemm_xw(const float* __restrict__ X,
                                               const float* __restrict__ W,
                                               float* __restrict__ Xp) {
    __shared__ float xs[ROWS_PER_BLOCK][D];
    const int r0  = blockIdx.x * ROWS_PER_BLOCK;
    const int tid = threadIdx.x;

    // Stage 8 rows of X (8 KiB) into LDS, coalesced float4 loads.
    // 8*256 = 2048 floats = 512 float4; 256 threads -> 2 each.
    {
        const float4* src = reinterpret_cast<const float4*>(X + (size_t)r0 * D);
        float4* dst = reinterpret_cast<float4*>(&xs[0][0]);
        #pragma unroll
        for (int i = 0; i < 2; ++i) dst[tid + i * 256] = src[tid + i * 256];
    }
    __syncthreads();

    const int c = tid;  // output column this thread owns
    float acc[ROWS_PER_BLOCK];
    #pragma unroll
    for (int r = 0; r < ROWS_PER_BLOCK; ++r) acc[r] = 0.f;

    for (int k = 0; k < D; ++k) {
        const float w = W[k * D + c];   // coalesced, L1/L2-resident (256 KiB)
        #pragma unroll
        for (int r = 0; r < ROWS_PER_BLOCK; ++r)
            acc[r] += xs[r][k] * w;     // xs broadcast across wave (free)
    }

    #pragma unroll
    for (int r = 0; r < ROWS_PER_BLOCK; ++r)
        Xp[(size_t)(r0 + r) * D + c] = acc[r];
}

// ---------------------------------------------------------------------------
// Kernel 2: scatter Xp rows into Xe  (Xe[e] += Xp[n])  — one wave per nnz
// ---------------------------------------------------------------------------
__global__ __launch_bounds__(256) void scatter_node_to_edge(
        const float* __restrict__ Xp,
        const int* __restrict__ node_idx,
        const int* __restrict__ edge_idx,
        float* __restrict__ Xe) {
    const int wave = (blockIdx.x * 256 + threadIdx.x) >> 6;
    const int lane = threadIdx.x & 63;
    if (wave >= NNZ) return;
    const int n = node_idx[wave];
    const int e = edge_idx[wave];
    const float4 v = *reinterpret_cast<const float4*>(Xp + (size_t)n * D + lane * 4);
    float* dst = Xe + (size_t)e * D + lane * 4;
    atomicAdd(dst + 0, v.x);
    atomicAdd(dst + 1, v.y);
    atomicAdd(dst + 2, v.z);
    atomicAdd(dst + 3, v.w);
}

// ---------------------------------------------------------------------------
// Kernel 3: scatter (Xe[e] * degE[e]) rows into Xv(=d_out)  — one wave per nnz
// ---------------------------------------------------------------------------
__global__ __launch_bounds__(256) void scatter_edge_to_node(
        const float* __restrict__ Xe,
        const float* __restrict__ degE,
        const int* __restrict__ node_idx,
        const int* __restrict__ edge_idx,
        float* __restrict__ Xv) {
    const int wave = (blockIdx.x * 256 + threadIdx.x) >> 6;
    const int lane = threadIdx.x & 63;
    if (wave >= NNZ) return;
    const int n = node_idx[wave];
    const int e = edge_idx[wave];
    const float s = degE[e];
    const float4 v = *reinterpret_cast<const float4*>(Xe + (size_t)e * D + lane * 4);
    float* dst = Xv + (size_t)n * D + lane * 4;
    atomicAdd(dst + 0, v.x * s);
    atomicAdd(dst + 1, v.y * s);
    atomicAdd(dst + 2, v.z * s);
    atomicAdd(dst + 3, v.w * s);
}

// ---------------------------------------------------------------------------
// Kernel 4: out = (1+eps)*Xp + degV[row]*Xv   (Xv already lives in d_out)
// ---------------------------------------------------------------------------
__global__ __launch_bounds__(256) void finalize(const float* __restrict__ Xp,
                                                const float* __restrict__ degV,
                                                const float* __restrict__ eps,
                                                float* __restrict__ out) {
    const size_t i = (size_t)blockIdx.x * 256 + threadIdx.x;  // float4 index
    if (i >= (size_t)N_NODES * D / 4) return;
    const int row = (int)(i / (D / 4));
    const float e  = 1.f + eps[0];
    const float dv = degV[row];
    const float4 xp = reinterpret_cast<const float4*>(Xp)[i];
    float4 xv = reinterpret_cast<float4*>(out)[i];
    xv.x = e * xp.x + dv * xv.x;
    xv.y = e * xp.y + dv * xv.y;
    xv.z = e * xp.z + dv * xv.z;
    xv.w = e * xp.w + dv * xv.w;
    reinterpret_cast<float4*>(out)[i] = xv;
}

// ---------------------------------------------------------------------------
extern "C" void kernel_launch(void* const* d_in, const int* in_sizes, int n_in,
                              void* d_out, int out_size, void* d_ws, size_t ws_size,
                              hipStream_t stream) {
    const float* X        = (const float*)d_in[0];
    const float* W        = (const float*)d_in[1];
    const float* eps      = (const float*)d_in[2];
    const float* degE     = (const float*)d_in[3];
    const float* degV     = (const float*)d_in[4];
    const int*   node_idx = (const int*)d_in[5];
    const int*   edge_idx = (const int*)d_in[6];

    float* out = (float*)d_out;

    // workspace layout: Xp [N_NODES*D] f32, then Xe [N_EDGES*D] f32
    const size_t XP_BYTES = (size_t)N_NODES * D * sizeof(float);
    const size_t XE_BYTES = (size_t)N_EDGES * D * sizeof(float);
    float* Xp = (float*)d_ws;
    float* Xe = (float*)((char*)d_ws + XP_BYTES);

    // zero accumulation targets (capture-legal async memsets)
    hipMemsetAsync(Xe, 0, XE_BYTES, stream);
    hipMemsetAsync(d_out, 0, (size_t)out_size * sizeof(float), stream);

    // 1) Xp = X @ W
    gemm_xw<<<N_NODES / ROWS_PER_BLOCK, 256, 0, stream>>>(X, W, Xp);

    // 2) Xe += scatter(Xp)
    scatter_node_to_edge<<<(NNZ * 64 + 255) / 256, 256, 0, stream>>>(
        Xp, node_idx, edge_idx, Xe);

    // 3) Xv(=out) += scatter(Xe * degE)
    scatter_edge_to_node<<<(NNZ * 64 + 255) / 256, 256, 0, stream>>>(
        Xe, degE, node_idx, edge_idx, out);

    // 4) out = (1+eps)*Xp + degV*out
    finalize<<<(N_NODES * D / 4 + 255) / 256, 256, 0, stream>>>(
        Xp, degV, eps, out);
}

// Round 2
// 692.472 us; speedup vs baseline: 8.1486x; 8.1486x over previous
//
#include <hip/hip_runtime.h>

#define N_NODES 100000
#define N_EDGES 50000
#define NNZ     800000
#define D       256

#define ROWS_PER_BLOCK 8
#define SCAN_TILE 1024   // elems per block in scan_a (256 thr x 4)

// ---------------------------------------------------------------------------
// Kernel 1: Xp = X @ W   (f32, LDS-staged rows, thread-per-column)
// ---------------------------------------------------------------------------
__global__ __launch_bounds__(256) void gemm_xw(const float* __restrict__ X,
                                               const float* __restrict__ W,
                                               float* __restrict__ Xp) {
    __shared__ float xs[ROWS_PER_BLOCK][D];
    const int r0  = blockIdx.x * ROWS_PER_BLOCK;
    const int tid = threadIdx.x;

    {
        const float4* src = reinterpret_cast<const float4*>(X + (size_t)r0 * D);
        float4* dst = reinterpret_cast<float4*>(&xs[0][0]);
        #pragma unroll
        for (int i = 0; i < 2; ++i) dst[tid + i * 256] = src[tid + i * 256];
    }
    __syncthreads();

    const int c = tid;
    float acc[ROWS_PER_BLOCK];
    #pragma unroll
    for (int r = 0; r < ROWS_PER_BLOCK; ++r) acc[r] = 0.f;

    for (int k = 0; k < D; ++k) {
        const float w = W[k * D + c];
        #pragma unroll
        for (int r = 0; r < ROWS_PER_BLOCK; ++r)
            acc[r] += xs[r][k] * w;
    }

    #pragma unroll
    for (int r = 0; r < ROWS_PER_BLOCK; ++r)
        Xp[(size_t)(r0 + r) * D + c] = acc[r];
}

// ---------------------------------------------------------------------------
// CSR build: histogram -> 3-kernel exclusive scan -> fused fill
// ---------------------------------------------------------------------------
__global__ __launch_bounds__(256) void hist(const int* __restrict__ idx,
                                            int* __restrict__ cnt, int nnz) {
    const int i = blockIdx.x * 256 + threadIdx.x;
    if (i < nnz) atomicAdd(&cnt[idx[i]], 1);
}

// per-block exclusive scan over tiles of 1024 (256 thr x 4 contiguous)
__global__ __launch_bounds__(256) void scan_a(const int* __restrict__ cnt,
                                              int* __restrict__ off,
                                              int* __restrict__ bsum, int n) {
    __shared__ int s[256];
    const int t = threadIdx.x;
    const int base = blockIdx.x * SCAN_TILE + t * 4;
    int v[4];
    #pragma unroll
    for (int k = 0; k < 4; ++k) v[k] = (base + k < n) ? cnt[base + k] : 0;
    const int tsum = v[0] + v[1] + v[2] + v[3];
    s[t] = tsum;
    __syncthreads();
    #pragma unroll
    for (int d = 1; d < 256; d <<= 1) {
        const int x = (t >= d) ? s[t - d] : 0;
        __syncthreads();
        s[t] += x;
        __syncthreads();
    }
    if (t == 255) bsum[blockIdx.x] = s[255];
    int run = s[t] - tsum;  // exclusive prefix of this thread within block
    #pragma unroll
    for (int k = 0; k < 4; ++k) {
        if (base + k < n) off[base + k] = run;
        run += v[k];
    }
}

// single-block exclusive scan of block sums (nblocks <= 256); writes total
__global__ __launch_bounds__(256) void scan_b(int* __restrict__ bsum, int nblocks,
                                              int* __restrict__ off, int n) {
    __shared__ int s[256];
    const int t = threadIdx.x;
    const int v = (t < nblocks) ? bsum[t] : 0;
    s[t] = v;
    __syncthreads();
    #pragma unroll
    for (int d = 1; d < 256; d <<= 1) {
        const int x = (t >= d) ? s[t - d] : 0;
        __syncthreads();
        s[t] += x;
        __syncthreads();
    }
    if (t < nblocks) bsum[t] = s[t] - v;
    if (t == 255) off[n] = s[255];  // grand total
}

// add block bases; also copy to cursor array for the fill phase
__global__ __launch_bounds__(256) void scan_c(int* __restrict__ off,
                                              const int* __restrict__ bsum,
                                              int* __restrict__ cur, int n) {
    const int i = blockIdx.x * 256 + threadIdx.x;
    if (i >= n) return;
    const int o = off[i] + bsum[i / SCAN_TILE];
    off[i] = o;
    cur[i] = o;
}

// fused fill: src[p] = other-side index (removes one indirection in gather)
__global__ __launch_bounds__(256) void fill_csr(const int* __restrict__ seg_idx,
                                                const int* __restrict__ val_idx,
                                                int* __restrict__ cur,
                                                int* __restrict__ src, int nnz) {
    const int i = blockIdx.x * 256 + threadIdx.x;
    if (i >= nnz) return;
    const int p = atomicAdd(&cur[seg_idx[i]], 1);
    src[p] = val_idx[i];
}

// ---------------------------------------------------------------------------
// Stage 1: Xe[e] = degE[e] * sum_{j in edge e} Xp[esrc[j]]   (wave per edge)
// ---------------------------------------------------------------------------
__global__ __launch_bounds__(256) void edge_gather(
        const float* __restrict__ Xp, const int* __restrict__ eoff,
        const int* __restrict__ esrc, const float* __restrict__ degE,
        float* __restrict__ Xe) {
    const int e = (blockIdx.x * 256 + threadIdx.x) >> 6;
    const int lane = threadIdx.x & 63;
    if (e >= N_EDGES) return;
    const int beg = eoff[e], end = eoff[e + 1];
    float ax = 0.f, ay = 0.f, az = 0.f, aw = 0.f;
    for (int j = beg; j < end; ++j) {
        const int n = esrc[j];
        const float4 v = *reinterpret_cast<const float4*>(Xp + (size_t)n * D + lane * 4);
        ax += v.x; ay += v.y; az += v.z; aw += v.w;
    }
    const float s = degE[e];
    const float4 o = make_float4(ax * s, ay * s, az * s, aw * s);
    *reinterpret_cast<float4*>(Xe + (size_t)e * D + lane * 4) = o;
}

// ---------------------------------------------------------------------------
// Stage 2 (fused finalize):
//   out[n] = (1+eps)*Xp[n] + degV[n] * sum_{j in node n} Xe[vsrc[j]]
// ---------------------------------------------------------------------------
__global__ __launch_bounds__(256) void node_gather(
        const float* __restrict__ Xp, const float* __restrict__ Xe,
        const int* __restrict__ voff, const int* __restrict__ vsrc,
        const float* __restrict__ degV, const float* __restrict__ eps,
        float* __restrict__ out) {
    const int nd = (blockIdx.x * 256 + threadIdx.x) >> 6;
    const int lane = threadIdx.x & 63;
    if (nd >= N_NODES) return;
    const int beg = voff[nd], end = voff[nd + 1];
    float ax = 0.f, ay = 0.f, az = 0.f, aw = 0.f;
    for (int j = beg; j < end; ++j) {
        const int e = vsrc[j];
        const float4 v = *reinterpret_cast<const float4*>(Xe + (size_t)e * D + lane * 4);
        ax += v.x; ay += v.y; az += v.z; aw += v.w;
    }
    const float dv = degV[nd];
    const float ep = 1.f + eps[0];
    const float4 xp = *reinterpret_cast<const float4*>(Xp + (size_t)nd * D + lane * 4);
    float4 o;
    o.x = ep * xp.x + dv * ax;
    o.y = ep * xp.y + dv * ay;
    o.z = ep * xp.z + dv * az;
    o.w = ep * xp.w + dv * aw;
    *reinterpret_cast<float4*>(out + (size_t)nd * D + lane * 4) = o;
}

// ---------------------------------------------------------------------------
extern "C" void kernel_launch(void* const* d_in, const int* in_sizes, int n_in,
                              void* d_out, int out_size, void* d_ws, size_t ws_size,
                              hipStream_t stream) {
    const float* X        = (const float*)d_in[0];
    const float* W        = (const float*)d_in[1];
    const float* eps      = (const float*)d_in[2];
    const float* degE     = (const float*)d_in[3];
    const float* degV     = (const float*)d_in[4];
    const int*   node_idx = (const int*)d_in[5];
    const int*   edge_idx = (const int*)d_in[6];

    float* out = (float*)d_out;

    // ---- workspace layout ----
    char* p = (char*)d_ws;
    float* Xp  = (float*)p;  p += (size_t)N_NODES * D * sizeof(float);   // 102.4 MB
    float* Xe  = (float*)p;  p += (size_t)N_EDGES * D * sizeof(float);   //  51.2 MB
    int* eoff  = (int*)p;    p += ((size_t)N_EDGES + 16) * sizeof(int);
    int* voff  = (int*)p;    p += ((size_t)N_NODES + 16) * sizeof(int);
    int* ecur  = (int*)p;    p += (size_t)N_EDGES * sizeof(int);
    int* vcur  = (int*)p;    p += (size_t)N_NODES * sizeof(int);
    int* esrc  = (int*)p;    p += (size_t)NNZ * sizeof(int);
    int* vsrc  = (int*)p;    p += (size_t)NNZ * sizeof(int);
    int* ebsum = (int*)p;    p += 256 * sizeof(int);
    int* vbsum = (int*)p;    p += 256 * sizeof(int);

    const int EB = (N_EDGES + SCAN_TILE - 1) / SCAN_TILE;   // 49
    const int VB = (N_NODES + SCAN_TILE - 1) / SCAN_TILE;   // 98
    const int NNZ_BLOCKS = (NNZ + 255) / 256;               // 3125

    // 1) GEMM (independent of CSR build)
    gemm_xw<<<N_NODES / ROWS_PER_BLOCK, 256, 0, stream>>>(X, W, Xp);

    // 2) CSR build for both directions (counts live in ecur/vcur, then
    //    scan_c turns them into cursor copies of the offsets)
    hipMemsetAsync(ecur, 0, (size_t)N_EDGES * sizeof(int), stream);
    hipMemsetAsync(vcur, 0, (size_t)N_NODES * sizeof(int), stream);
    hist<<<NNZ_BLOCKS, 256, 0, stream>>>(edge_idx, ecur, NNZ);
    hist<<<NNZ_BLOCKS, 256, 0, stream>>>(node_idx, vcur, NNZ);

    scan_a<<<EB, 256, 0, stream>>>(ecur, eoff, ebsum, N_EDGES);
    scan_b<<<1, 256, 0, stream>>>(ebsum, EB, eoff, N_EDGES);
    scan_c<<<(N_EDGES + 255) / 256, 256, 0, stream>>>(eoff, ebsum, ecur, N_EDGES);

    scan_a<<<VB, 256, 0, stream>>>(vcur, voff, vbsum, N_NODES);
    scan_b<<<1, 256, 0, stream>>>(vbsum, VB, voff, N_NODES);
    scan_c<<<(N_NODES + 255) / 256, 256, 0, stream>>>(voff, vbsum, vcur, N_NODES);

    fill_csr<<<NNZ_BLOCKS, 256, 0, stream>>>(edge_idx, node_idx, ecur, esrc, NNZ);
    fill_csr<<<NNZ_BLOCKS, 256, 0, stream>>>(node_idx, edge_idx, vcur, vsrc, NNZ);

    // 3) nodes -> edges (gather, fused degE)
    edge_gather<<<(N_EDGES * 64 + 255) / 256, 256, 0, stream>>>(
        Xp, eoff, esrc, degE, Xe);

    // 4) edges -> nodes (gather, fused degV + (1+eps)*Xp residual)
    node_gather<<<(N_NODES * 64 + 255) / 256, 256, 0, stream>>>(
        Xp, Xe, voff, vsrc, degV, eps, out);
}

// Round 3
// 485.540 us; speedup vs baseline: 11.6215x; 1.4262x over previous
//
#include <hip/hip_runtime.h>

#define N_NODES 100000
#define N_EDGES 50000
#define NNZ     800000
#define D       256

#define SCAN_TILE 1024   // elems per block in scan_a (256 thr x 4)
#define BM 64            // gemm rows per block

typedef __bf16 bf16x8 __attribute__((ext_vector_type(8)));
typedef float  f32x4  __attribute__((ext_vector_type(4)));

// ---------------------------------------------------------------------------
// Kernel 0: pack W (f32 [256][256]) into bf16 MFMA b-fragment order.
// Wp index: ((ks*16 + n16)*64 + lane) -> 8 bf16 covering
//   k = ks*32 + (lane>>4)*8 + j,  col = n16*16 + (lane&15)
// ---------------------------------------------------------------------------
__global__ __launch_bounds__(256) void pack_W(const float* __restrict__ W,
                                              bf16x8* __restrict__ Wp) {
    const int t = blockIdx.x * 256 + threadIdx.x;   // 8192 total
    if (t >= 8 * 16 * 64) return;
    const int ks  = t >> 10;
    const int n16 = (t >> 6) & 15;
    const int l   = t & 63;
    const int kb  = ks * 32 + (l >> 4) * 8;
    const int col = n16 * 16 + (l & 15);
    bf16x8 v;
    #pragma unroll
    for (int j = 0; j < 8; ++j) v[j] = (__bf16)W[(size_t)(kb + j) * D + col];
    Wp[t] = v;
}

// ---------------------------------------------------------------------------
// Kernel 1: Xp = X @ W  via bf16 MFMA (f32 accumulate).
// Block: 64 rows x 256 cols, 4 waves, each wave 64 rows x 64 cols.
// ---------------------------------------------------------------------------
__global__ __launch_bounds__(256) void gemm_mfma(const float* __restrict__ X,
                                                 const bf16x8* __restrict__ Wp,
                                                 float* __restrict__ Xp) {
    __shared__ __bf16 As[BM][D];   // 32 KB, XOR-swizzled in 16B chunks
    const int tid = threadIdx.x;
    const int r0  = blockIdx.x * BM;

    // ---- stage 64x256 f32 -> bf16 LDS, swizzled ----
    // chunk = 8 bf16 (16 B); 32 chunks/row; 2048 chunks; 8 per thread.
    #pragma unroll
    for (int i = 0; i < 8; ++i) {
        const int g   = tid + i * 256;
        const int row = g >> 5;
        const int cc  = g & 31;
        const int gr  = min(r0 + row, N_NODES - 1);
        const float4 f0 = reinterpret_cast<const float4*>(X)[(size_t)gr * 64 + cc * 2 + 0];
        const float4 f1 = reinterpret_cast<const float4*>(X)[(size_t)gr * 64 + cc * 2 + 1];
        bf16x8 v;
        v[0] = (__bf16)f0.x; v[1] = (__bf16)f0.y; v[2] = (__bf16)f0.z; v[3] = (__bf16)f0.w;
        v[4] = (__bf16)f1.x; v[5] = (__bf16)f1.y; v[6] = (__bf16)f1.z; v[7] = (__bf16)f1.w;
        const int sw = cc ^ (row & 7);
        *reinterpret_cast<bf16x8*>(&As[row][sw * 8]) = v;
    }
    __syncthreads();

    const int w = tid >> 6;     // wave 0..3 -> cols w*64..w*64+63
    const int l = tid & 63;

    f32x4 acc[4][4];
    #pragma unroll
    for (int mt = 0; mt < 4; ++mt)
        #pragma unroll
        for (int nt = 0; nt < 4; ++nt) acc[mt][nt] = (f32x4){0.f, 0.f, 0.f, 0.f};

    #pragma unroll
    for (int ks = 0; ks < 8; ++ks) {
        bf16x8 a[4];
        #pragma unroll
        for (int mt = 0; mt < 4; ++mt) {
            const int row = mt * 16 + (l & 15);
            const int ch  = (ks * 4 + (l >> 4)) ^ (row & 7);
            a[mt] = *reinterpret_cast<const bf16x8*>(&As[row][ch * 8]);
        }
        #pragma unroll
        for (int nt = 0; nt < 4; ++nt) {
            const bf16x8 b = Wp[(ks * 16 + w * 4 + nt) * 64 + l];
            #pragma unroll
            for (int mt = 0; mt < 4; ++mt)
                acc[mt][nt] = __builtin_amdgcn_mfma_f32_16x16x32_bf16(a[mt], b, acc[mt][nt], 0, 0, 0);
        }
    }

    // ---- store: C row = (l>>4)*4 + reg, col = l&15 ----
    #pragma unroll
    for (int mt = 0; mt < 4; ++mt) {
        const int rbase = r0 + mt * 16 + (l >> 4) * 4;
        #pragma unroll
        for (int reg = 0; reg < 4; ++reg) {
            const int r = rbase + reg;
            if (r >= N_NODES) continue;
            #pragma unroll
            for (int nt = 0; nt < 4; ++nt)
                Xp[(size_t)r * D + w * 64 + nt * 16 + (l & 15)] = acc[mt][nt][reg];
        }
    }
}

// ---------------------------------------------------------------------------
// CSR build: histogram -> 3-kernel exclusive scan -> fused fill
// ---------------------------------------------------------------------------
__global__ __launch_bounds__(256) void hist(const int* __restrict__ idx,
                                            int* __restrict__ cnt, int nnz) {
    const int i = blockIdx.x * 256 + threadIdx.x;
    if (i < nnz) atomicAdd(&cnt[idx[i]], 1);
}

__global__ __launch_bounds__(256) void scan_a(const int* __restrict__ cnt,
                                              int* __restrict__ off,
                                              int* __restrict__ bsum, int n) {
    __shared__ int s[256];
    const int t = threadIdx.x;
    const int base = blockIdx.x * SCAN_TILE + t * 4;
    int v[4];
    #pragma unroll
    for (int k = 0; k < 4; ++k) v[k] = (base + k < n) ? cnt[base + k] : 0;
    const int tsum = v[0] + v[1] + v[2] + v[3];
    s[t] = tsum;
    __syncthreads();
    #pragma unroll
    for (int d = 1; d < 256; d <<= 1) {
        const int x = (t >= d) ? s[t - d] : 0;
        __syncthreads();
        s[t] += x;
        __syncthreads();
    }
    if (t == 255) bsum[blockIdx.x] = s[255];
    int run = s[t] - tsum;
    #pragma unroll
    for (int k = 0; k < 4; ++k) {
        if (base + k < n) off[base + k] = run;
        run += v[k];
    }
}

__global__ __launch_bounds__(256) void scan_b(int* __restrict__ bsum, int nblocks,
                                              int* __restrict__ off, int n) {
    __shared__ int s[256];
    const int t = threadIdx.x;
    const int v = (t < nblocks) ? bsum[t] : 0;
    s[t] = v;
    __syncthreads();
    #pragma unroll
    for (int d = 1; d < 256; d <<= 1) {
        const int x = (t >= d) ? s[t - d] : 0;
        __syncthreads();
        s[t] += x;
        __syncthreads();
    }
    if (t < nblocks) bsum[t] = s[t] - v;
    if (t == 255) off[n] = s[255];
}

__global__ __launch_bounds__(256) void scan_c(int* __restrict__ off,
                                              const int* __restrict__ bsum,
                                              int* __restrict__ cur, int n) {
    const int i = blockIdx.x * 256 + threadIdx.x;
    if (i >= n) return;
    const int o = off[i] + bsum[i / SCAN_TILE];
    off[i] = o;
    cur[i] = o;
}

__global__ __launch_bounds__(256) void fill_csr(const int* __restrict__ seg_idx,
                                                const int* __restrict__ val_idx,
                                                int* __restrict__ cur,
                                                int* __restrict__ src, int nnz) {
    const int i = blockIdx.x * 256 + threadIdx.x;
    if (i >= nnz) return;
    const int p = atomicAdd(&cur[seg_idx[i]], 1);
    src[p] = val_idx[i];
}

// ---------------------------------------------------------------------------
// Stage 1: Xe[e] = degE[e] * sum_{j in edge e} Xp[esrc[j]]   (wave per edge)
// ---------------------------------------------------------------------------
__global__ __launch_bounds__(256) void edge_gather(
        const float* __restrict__ Xp, const int* __restrict__ eoff,
        const int* __restrict__ esrc, const float* __restrict__ degE,
        float* __restrict__ Xe) {
    const int e = (blockIdx.x * 256 + threadIdx.x) >> 6;
    const int lane = threadIdx.x & 63;
    if (e >= N_EDGES) return;
    const int beg = eoff[e], end = eoff[e + 1];
    float ax = 0.f, ay = 0.f, az = 0.f, aw = 0.f;
    for (int j = beg; j < end; ++j) {
        const int n = esrc[j];
        const float4 v = *reinterpret_cast<const float4*>(Xp + (size_t)n * D + lane * 4);
        ax += v.x; ay += v.y; az += v.z; aw += v.w;
    }
    const float s = degE[e];
    const float4 o = make_float4(ax * s, ay * s, az * s, aw * s);
    *reinterpret_cast<float4*>(Xe + (size_t)e * D + lane * 4) = o;
}

// ---------------------------------------------------------------------------
// Stage 2 (fused finalize):
//   out[n] = (1+eps)*Xp[n] + degV[n] * sum_{j in node n} Xe[vsrc[j]]
// ---------------------------------------------------------------------------
__global__ __launch_bounds__(256) void node_gather(
        const float* __restrict__ Xp, const float* __restrict__ Xe,
        const int* __restrict__ voff, const int* __restrict__ vsrc,
        const float* __restrict__ degV, const float* __restrict__ eps,
        float* __restrict__ out) {
    const int nd = (blockIdx.x * 256 + threadIdx.x) >> 6;
    const int lane = threadIdx.x & 63;
    if (nd >= N_NODES) return;
    const int beg = voff[nd], end = voff[nd + 1];
    float ax = 0.f, ay = 0.f, az = 0.f, aw = 0.f;
    for (int j = beg; j < end; ++j) {
        const int e = vsrc[j];
        const float4 v = *reinterpret_cast<const float4*>(Xe + (size_t)e * D + lane * 4);
        ax += v.x; ay += v.y; az += v.z; aw += v.w;
    }
    const float dv = degV[nd];
    const float ep = 1.f + eps[0];
    const float4 xp = *reinterpret_cast<const float4*>(Xp + (size_t)nd * D + lane * 4);
    float4 o;
    o.x = ep * xp.x + dv * ax;
    o.y = ep * xp.y + dv * ay;
    o.z = ep * xp.z + dv * az;
    o.w = ep * xp.w + dv * aw;
    *reinterpret_cast<float4*>(out + (size_t)nd * D + lane * 4) = o;
}

// ---------------------------------------------------------------------------
extern "C" void kernel_launch(void* const* d_in, const int* in_sizes, int n_in,
                              void* d_out, int out_size, void* d_ws, size_t ws_size,
                              hipStream_t stream) {
    const float* X        = (const float*)d_in[0];
    const float* W        = (const float*)d_in[1];
    const float* eps      = (const float*)d_in[2];
    const float* degE     = (const float*)d_in[3];
    const float* degV     = (const float*)d_in[4];
    const int*   node_idx = (const int*)d_in[5];
    const int*   edge_idx = (const int*)d_in[6];

    float* out = (float*)d_out;

    // ---- workspace layout ----
    char* p = (char*)d_ws;
    float*  Xp  = (float*)p;  p += (size_t)N_NODES * D * sizeof(float);   // 102.4 MB
    float*  Xe  = (float*)p;  p += (size_t)N_EDGES * D * sizeof(float);   //  51.2 MB
    bf16x8* Wp  = (bf16x8*)p; p += (size_t)8 * 16 * 64 * sizeof(bf16x8);  // 128 KB
    int* eoff  = (int*)p;    p += ((size_t)N_EDGES + 16) * sizeof(int);
    int* voff  = (int*)p;    p += ((size_t)N_NODES + 16) * sizeof(int);
    int* ecur  = (int*)p;    p += (size_t)N_EDGES * sizeof(int);
    int* vcur  = (int*)p;    p += (size_t)N_NODES * sizeof(int);
    int* esrc  = (int*)p;    p += (size_t)NNZ * sizeof(int);
    int* vsrc  = (int*)p;    p += (size_t)NNZ * sizeof(int);
    int* ebsum = (int*)p;    p += 256 * sizeof(int);
    int* vbsum = (int*)p;    p += 256 * sizeof(int);

    const int EB = (N_EDGES + SCAN_TILE - 1) / SCAN_TILE;   // 49
    const int VB = (N_NODES + SCAN_TILE - 1) / SCAN_TILE;   // 98
    const int NNZ_BLOCKS = (NNZ + 255) / 256;               // 3125

    // 1) GEMM (bf16 MFMA): pack W, then tiled MFMA GEMM
    pack_W<<<32, 256, 0, stream>>>(W, Wp);
    gemm_mfma<<<(N_NODES + BM - 1) / BM, 256, 0, stream>>>(X, Wp, Xp);

    // 2) CSR build for both directions
    hipMemsetAsync(ecur, 0, (size_t)N_EDGES * sizeof(int), stream);
    hipMemsetAsync(vcur, 0, (size_t)N_NODES * sizeof(int), stream);
    hist<<<NNZ_BLOCKS, 256, 0, stream>>>(edge_idx, ecur, NNZ);
    hist<<<NNZ_BLOCKS, 256, 0, stream>>>(node_idx, vcur, NNZ);

    scan_a<<<EB, 256, 0, stream>>>(ecur, eoff, ebsum, N_EDGES);
    scan_b<<<1, 256, 0, stream>>>(ebsum, EB, eoff, N_EDGES);
    scan_c<<<(N_EDGES + 255) / 256, 256, 0, stream>>>(eoff, ebsum, ecur, N_EDGES);

    scan_a<<<VB, 256, 0, stream>>>(vcur, voff, vbsum, N_NODES);
    scan_b<<<1, 256, 0, stream>>>(vbsum, VB, voff, N_NODES);
    scan_c<<<(N_NODES + 255) / 256, 256, 0, stream>>>(voff, vbsum, vcur, N_NODES);

    fill_csr<<<NNZ_BLOCKS, 256, 0, stream>>>(edge_idx, node_idx, ecur, esrc, NNZ);
    fill_csr<<<NNZ_BLOCKS, 256, 0, stream>>>(node_idx, edge_idx, vcur, vsrc, NNZ);

    // 3) nodes -> edges (gather, fused degE)
    edge_gather<<<(N_EDGES * 64 + 255) / 256, 256, 0, stream>>>(
        Xp, eoff, esrc, degE, Xe);

    // 4) edges -> nodes (gather, fused degV + (1+eps)*Xp residual)
    node_gather<<<(N_NODES * 64 + 255) / 256, 256, 0, stream>>>(
        Xp, Xe, voff, vsrc, degV, eps, out);
}

// Round 4
// 420.049 us; speedup vs baseline: 13.4335x; 1.1559x over previous
//
#include <hip/hip_runtime.h>

#define N_NODES 100000
#define N_EDGES 50000
#define NNZ     800000
#define D       256

#define SCAN_TILE 1024   // elems per block in scan_a (256 thr x 4)
#define BM 64            // gemm rows per block

typedef __bf16 bf16x8 __attribute__((ext_vector_type(8)));
typedef __bf16 bf16x4 __attribute__((ext_vector_type(4)));
typedef float  f32x4  __attribute__((ext_vector_type(4)));

__device__ __forceinline__ float bf2f(unsigned short u) {
    union { unsigned int i; float f; } v;
    v.i = ((unsigned int)u) << 16;
    return v.f;
}

// ---------------------------------------------------------------------------
// Kernel 0: pack W (f32 [256][256]) into bf16 MFMA b-fragment order.
// ---------------------------------------------------------------------------
__global__ __launch_bounds__(256) void pack_W(const float* __restrict__ W,
                                              bf16x8* __restrict__ Wp) {
    const int t = blockIdx.x * 256 + threadIdx.x;   // 8192 total
    if (t >= 8 * 16 * 64) return;
    const int ks  = t >> 10;
    const int n16 = (t >> 6) & 15;
    const int l   = t & 63;
    const int kb  = ks * 32 + (l >> 4) * 8;
    const int col = n16 * 16 + (l & 15);
    bf16x8 v;
    #pragma unroll
    for (int j = 0; j < 8; ++j) v[j] = (__bf16)W[(size_t)(kb + j) * D + col];
    Wp[t] = v;
}

// ---------------------------------------------------------------------------
// Kernel 1: Xp(bf16) = X @ W  via bf16 MFMA (f32 accumulate).
// Block: 64 rows x 256 cols, 4 waves, each wave 64 rows x 64 cols.
// ---------------------------------------------------------------------------
__global__ __launch_bounds__(256) void gemm_mfma(const float* __restrict__ X,
                                                 const bf16x8* __restrict__ Wp,
                                                 __bf16* __restrict__ Xpb) {
    __shared__ __bf16 As[BM][D];   // 32 KB, XOR-swizzled in 16B chunks
    const int tid = threadIdx.x;
    const int r0  = blockIdx.x * BM;

    #pragma unroll
    for (int i = 0; i < 8; ++i) {
        const int g   = tid + i * 256;
        const int row = g >> 5;
        const int cc  = g & 31;
        const int gr  = min(r0 + row, N_NODES - 1);
        const float4 f0 = reinterpret_cast<const float4*>(X)[(size_t)gr * 64 + cc * 2 + 0];
        const float4 f1 = reinterpret_cast<const float4*>(X)[(size_t)gr * 64 + cc * 2 + 1];
        bf16x8 v;
        v[0] = (__bf16)f0.x; v[1] = (__bf16)f0.y; v[2] = (__bf16)f0.z; v[3] = (__bf16)f0.w;
        v[4] = (__bf16)f1.x; v[5] = (__bf16)f1.y; v[6] = (__bf16)f1.z; v[7] = (__bf16)f1.w;
        const int sw = cc ^ (row & 7);
        *reinterpret_cast<bf16x8*>(&As[row][sw * 8]) = v;
    }
    __syncthreads();

    const int w = tid >> 6;     // wave 0..3 -> cols w*64..w*64+63
    const int l = tid & 63;

    f32x4 acc[4][4];
    #pragma unroll
    for (int mt = 0; mt < 4; ++mt)
        #pragma unroll
        for (int nt = 0; nt < 4; ++nt) acc[mt][nt] = (f32x4){0.f, 0.f, 0.f, 0.f};

    #pragma unroll
    for (int ks = 0; ks < 8; ++ks) {
        bf16x8 a[4];
        #pragma unroll
        for (int mt = 0; mt < 4; ++mt) {
            const int row = mt * 16 + (l & 15);
            const int ch  = (ks * 4 + (l >> 4)) ^ (row & 7);
            a[mt] = *reinterpret_cast<const bf16x8*>(&As[row][ch * 8]);
        }
        #pragma unroll
        for (int nt = 0; nt < 4; ++nt) {
            const bf16x8 b = Wp[(ks * 16 + w * 4 + nt) * 64 + l];
            #pragma unroll
            for (int mt = 0; mt < 4; ++mt)
                acc[mt][nt] = __builtin_amdgcn_mfma_f32_16x16x32_bf16(a[mt], b, acc[mt][nt], 0, 0, 0);
        }
    }

    // store bf16: C row = (l>>4)*4 + reg, col = l&15
    #pragma unroll
    for (int mt = 0; mt < 4; ++mt) {
        const int rbase = r0 + mt * 16 + (l >> 4) * 4;
        #pragma unroll
        for (int reg = 0; reg < 4; ++reg) {
            const int r = rbase + reg;
            if (r >= N_NODES) continue;
            #pragma unroll
            for (int nt = 0; nt < 4; ++nt)
                Xpb[(size_t)r * D + w * 64 + nt * 16 + (l & 15)] = (__bf16)acc[mt][nt][reg];
        }
    }
}

// ---------------------------------------------------------------------------
// CSR build: fused histogram -> 3-kernel exclusive scan x2 -> fused fill
// ---------------------------------------------------------------------------
__global__ __launch_bounds__(256) void hist2(const int* __restrict__ edge_idx,
                                             const int* __restrict__ node_idx,
                                             int* __restrict__ ecnt,
                                             int* __restrict__ vcnt, int nnz) {
    const int i = blockIdx.x * 256 + threadIdx.x;
    if (i >= nnz) return;
    atomicAdd(&ecnt[edge_idx[i]], 1);
    atomicAdd(&vcnt[node_idx[i]], 1);
}

__global__ __launch_bounds__(256) void scan_a(const int* __restrict__ cnt,
                                              int* __restrict__ off,
                                              int* __restrict__ bsum, int n) {
    __shared__ int s[256];
    const int t = threadIdx.x;
    const int base = blockIdx.x * SCAN_TILE + t * 4;
    int v[4];
    #pragma unroll
    for (int k = 0; k < 4; ++k) v[k] = (base + k < n) ? cnt[base + k] : 0;
    const int tsum = v[0] + v[1] + v[2] + v[3];
    s[t] = tsum;
    __syncthreads();
    #pragma unroll
    for (int d = 1; d < 256; d <<= 1) {
        const int x = (t >= d) ? s[t - d] : 0;
        __syncthreads();
        s[t] += x;
        __syncthreads();
    }
    if (t == 255) bsum[blockIdx.x] = s[255];
    int run = s[t] - tsum;
    #pragma unroll
    for (int k = 0; k < 4; ++k) {
        if (base + k < n) off[base + k] = run;
        run += v[k];
    }
}

__global__ __launch_bounds__(256) void scan_b(int* __restrict__ bsum, int nblocks,
                                              int* __restrict__ off, int n) {
    __shared__ int s[256];
    const int t = threadIdx.x;
    const int v = (t < nblocks) ? bsum[t] : 0;
    s[t] = v;
    __syncthreads();
    #pragma unroll
    for (int d = 1; d < 256; d <<= 1) {
        const int x = (t >= d) ? s[t - d] : 0;
        __syncthreads();
        s[t] += x;
        __syncthreads();
    }
    if (t < nblocks) bsum[t] = s[t] - v;
    if (t == 255) off[n] = s[255];
}

__global__ __launch_bounds__(256) void scan_c(int* __restrict__ off,
                                              const int* __restrict__ bsum,
                                              int* __restrict__ cur, int n) {
    const int i = blockIdx.x * 256 + threadIdx.x;
    if (i >= n) return;
    const int o = off[i] + bsum[i / SCAN_TILE];
    off[i] = o;
    cur[i] = o;
}

__global__ __launch_bounds__(256) void fill2(const int* __restrict__ edge_idx,
                                             const int* __restrict__ node_idx,
                                             int* __restrict__ ecur,
                                             int* __restrict__ vcur,
                                             int* __restrict__ esrc,
                                             int* __restrict__ vsrc, int nnz) {
    const int i = blockIdx.x * 256 + threadIdx.x;
    if (i >= nnz) return;
    const int e = edge_idx[i];
    const int n = node_idx[i];
    esrc[atomicAdd(&ecur[e], 1)] = n;
    vsrc[atomicAdd(&vcur[n], 1)] = e;
}

// ---------------------------------------------------------------------------
// Stage 1: Xe[e] = degE[e] * sum_{j in edge e} Xp[esrc[j]]   (wave per edge)
// bf16 rows: lane covers 4 columns (8B loads).
// ---------------------------------------------------------------------------
__global__ __launch_bounds__(256) void edge_gather(
        const __bf16* __restrict__ Xpb, const int* __restrict__ eoff,
        const int* __restrict__ esrc, const float* __restrict__ degE,
        __bf16* __restrict__ Xeb) {
    const int e = (blockIdx.x * 256 + threadIdx.x) >> 6;
    const int lane = threadIdx.x & 63;
    if (e >= N_EDGES) return;
    const int beg = eoff[e], end = eoff[e + 1];
    float a0 = 0.f, a1 = 0.f, a2 = 0.f, a3 = 0.f;
    const unsigned short* Xu = reinterpret_cast<const unsigned short*>(Xpb);
    int j = beg;
    for (; j + 1 < end; j += 2) {
        const int n0 = esrc[j];
        const int n1 = esrc[j + 1];
        const ushort4 u0 = *reinterpret_cast<const ushort4*>(Xu + (size_t)n0 * D + lane * 4);
        const ushort4 u1 = *reinterpret_cast<const ushort4*>(Xu + (size_t)n1 * D + lane * 4);
        a0 += bf2f(u0.x) + bf2f(u1.x);
        a1 += bf2f(u0.y) + bf2f(u1.y);
        a2 += bf2f(u0.z) + bf2f(u1.z);
        a3 += bf2f(u0.w) + bf2f(u1.w);
    }
    if (j < end) {
        const int n0 = esrc[j];
        const ushort4 u0 = *reinterpret_cast<const ushort4*>(Xu + (size_t)n0 * D + lane * 4);
        a0 += bf2f(u0.x); a1 += bf2f(u0.y); a2 += bf2f(u0.z); a3 += bf2f(u0.w);
    }
    const float s = degE[e];
    bf16x4 o;
    o[0] = (__bf16)(a0 * s); o[1] = (__bf16)(a1 * s);
    o[2] = (__bf16)(a2 * s); o[3] = (__bf16)(a3 * s);
    *reinterpret_cast<bf16x4*>(Xeb + (size_t)e * D + lane * 4) = o;
}

// ---------------------------------------------------------------------------
// Stage 2 (fused finalize):
//   out[n] = (1+eps)*Xp[n] + degV[n] * sum_{j in node n} Xe[vsrc[j]]
// ---------------------------------------------------------------------------
__global__ __launch_bounds__(256) void node_gather(
        const __bf16* __restrict__ Xpb, const __bf16* __restrict__ Xeb,
        const int* __restrict__ voff, const int* __restrict__ vsrc,
        const float* __restrict__ degV, const float* __restrict__ eps,
        float* __restrict__ out) {
    const int nd = (blockIdx.x * 256 + threadIdx.x) >> 6;
    const int lane = threadIdx.x & 63;
    if (nd >= N_NODES) return;
    const int beg = voff[nd], end = voff[nd + 1];
    const unsigned short* Xu = reinterpret_cast<const unsigned short*>(Xeb);
    // residual load early (independent of the gather chain)
    const ushort4 up = *reinterpret_cast<const ushort4*>(
        reinterpret_cast<const unsigned short*>(Xpb) + (size_t)nd * D + lane * 4);
    float a0 = 0.f, a1 = 0.f, a2 = 0.f, a3 = 0.f;
    int j = beg;
    for (; j + 1 < end; j += 2) {
        const int e0 = vsrc[j];
        const int e1 = vsrc[j + 1];
        const ushort4 u0 = *reinterpret_cast<const ushort4*>(Xu + (size_t)e0 * D + lane * 4);
        const ushort4 u1 = *reinterpret_cast<const ushort4*>(Xu + (size_t)e1 * D + lane * 4);
        a0 += bf2f(u0.x) + bf2f(u1.x);
        a1 += bf2f(u0.y) + bf2f(u1.y);
        a2 += bf2f(u0.z) + bf2f(u1.z);
        a3 += bf2f(u0.w) + bf2f(u1.w);
    }
    if (j < end) {
        const int e0 = vsrc[j];
        const ushort4 u0 = *reinterpret_cast<const ushort4*>(Xu + (size_t)e0 * D + lane * 4);
        a0 += bf2f(u0.x); a1 += bf2f(u0.y); a2 += bf2f(u0.z); a3 += bf2f(u0.w);
    }
    const float dv = degV[nd];
    const float ep = 1.f + eps[0];
    float4 o;
    o.x = ep * bf2f(up.x) + dv * a0;
    o.y = ep * bf2f(up.y) + dv * a1;
    o.z = ep * bf2f(up.z) + dv * a2;
    o.w = ep * bf2f(up.w) + dv * a3;
    *reinterpret_cast<float4*>(out + (size_t)nd * D + lane * 4) = o;
}

// ---------------------------------------------------------------------------
extern "C" void kernel_launch(void* const* d_in, const int* in_sizes, int n_in,
                              void* d_out, int out_size, void* d_ws, size_t ws_size,
                              hipStream_t stream) {
    const float* X        = (const float*)d_in[0];
    const float* W        = (const float*)d_in[1];
    const float* eps      = (const float*)d_in[2];
    const float* degE     = (const float*)d_in[3];
    const float* degV     = (const float*)d_in[4];
    const int*   node_idx = (const int*)d_in[5];
    const int*   edge_idx = (const int*)d_in[6];

    float* out = (float*)d_out;

    // ---- workspace layout ----
    char* p = (char*)d_ws;
    __bf16* Xpb = (__bf16*)p; p += (size_t)N_NODES * D * sizeof(__bf16);  // 51.2 MB
    __bf16* Xeb = (__bf16*)p; p += (size_t)N_EDGES * D * sizeof(__bf16);  // 25.6 MB
    bf16x8* Wp  = (bf16x8*)p; p += (size_t)8 * 16 * 64 * sizeof(bf16x8);  // 128 KB
    int* eoff  = (int*)p;    p += ((size_t)N_EDGES + 16) * sizeof(int);
    int* voff  = (int*)p;    p += ((size_t)N_NODES + 16) * sizeof(int);
    int* ecur  = (int*)p;    p += (size_t)N_EDGES * sizeof(int);          // ecur+vcur
    int* vcur  = (int*)p;    p += (size_t)N_NODES * sizeof(int);          //  contiguous
    int* esrc  = (int*)p;    p += (size_t)NNZ * sizeof(int);
    int* vsrc  = (int*)p;    p += (size_t)NNZ * sizeof(int);
    int* ebsum = (int*)p;    p += 256 * sizeof(int);
    int* vbsum = (int*)p;    p += 256 * sizeof(int);

    const int EB = (N_EDGES + SCAN_TILE - 1) / SCAN_TILE;   // 49
    const int VB = (N_NODES + SCAN_TILE - 1) / SCAN_TILE;   // 98
    const int NNZ_BLOCKS = (NNZ + 255) / 256;               // 3125

    // 1) GEMM (bf16 MFMA): pack W, then tiled MFMA GEMM -> bf16 Xp
    pack_W<<<32, 256, 0, stream>>>(W, Wp);
    gemm_mfma<<<(N_NODES + BM - 1) / BM, 256, 0, stream>>>(X, Wp, Xpb);

    // 2) CSR build for both directions (one memset covers ecur+vcur)
    hipMemsetAsync(ecur, 0, ((size_t)N_EDGES + N_NODES) * sizeof(int), stream);
    hist2<<<NNZ_BLOCKS, 256, 0, stream>>>(edge_idx, node_idx, ecur, vcur, NNZ);

    scan_a<<<EB, 256, 0, stream>>>(ecur, eoff, ebsum, N_EDGES);
    scan_b<<<1, 256, 0, stream>>>(ebsum, EB, eoff, N_EDGES);
    scan_c<<<(N_EDGES + 255) / 256, 256, 0, stream>>>(eoff, ebsum, ecur, N_EDGES);

    scan_a<<<VB, 256, 0, stream>>>(vcur, voff, vbsum, N_NODES);
    scan_b<<<1, 256, 0, stream>>>(vbsum, VB, voff, N_NODES);
    scan_c<<<(N_NODES + 255) / 256, 256, 0, stream>>>(voff, vbsum, vcur, N_NODES);

    fill2<<<NNZ_BLOCKS, 256, 0, stream>>>(edge_idx, node_idx, ecur, vcur,
                                          esrc, vsrc, NNZ);

    // 3) nodes -> edges (gather, fused degE)
    edge_gather<<<(N_EDGES * 64 + 255) / 256, 256, 0, stream>>>(
        Xpb, eoff, esrc, degE, Xeb);

    // 4) edges -> nodes (gather, fused degV + (1+eps)*Xp residual)
    node_gather<<<(N_NODES * 64 + 255) / 256, 256, 0, stream>>>(
        Xpb, Xeb, voff, vsrc, degV, eps, out);
}

// Round 5
// 275.586 us; speedup vs baseline: 20.4753x; 1.5242x over previous
//
#include <hip/hip_runtime.h>

#define N_NODES 100000
#define N_EDGES 50000
#define NNZ     800000
#define D       256

#define BM 64            // gemm rows per block

// bucket-sort CSR build
#define NB   98          // buckets per direction
#define ESH  9           // edge bucket shift: 512 keys/bucket (98*512 >= 50000)
#define VSH  10          // node bucket shift: 1024 keys/bucket (98*1024 >= 100000)
#define ENT  4096        // entries per multisplit/hist block
#define MS_BLOCKS ((NNZ + ENT - 1) / ENT)   // 196

typedef __bf16 bf16x8 __attribute__((ext_vector_type(8)));
typedef __bf16 bf16x4 __attribute__((ext_vector_type(4)));
typedef float  f32x4  __attribute__((ext_vector_type(4)));

__device__ __forceinline__ float bf2f(unsigned short u) {
    union { unsigned int i; float f; } v;
    v.i = ((unsigned int)u) << 16;
    return v.f;
}

// ---------------------------------------------------------------------------
// Kernel 0: pack W (f32 [256][256]) into bf16 MFMA b-fragment order.
// ---------------------------------------------------------------------------
__global__ __launch_bounds__(256) void pack_W(const float* __restrict__ W,
                                              bf16x8* __restrict__ Wp) {
    const int t = blockIdx.x * 256 + threadIdx.x;   // 8192 total
    if (t >= 8 * 16 * 64) return;
    const int ks  = t >> 10;
    const int n16 = (t >> 6) & 15;
    const int l   = t & 63;
    const int kb  = ks * 32 + (l >> 4) * 8;
    const int col = n16 * 16 + (l & 15);
    bf16x8 v;
    #pragma unroll
    for (int j = 0; j < 8; ++j) v[j] = (__bf16)W[(size_t)(kb + j) * D + col];
    Wp[t] = v;
}

// ---------------------------------------------------------------------------
// Kernel 1: Xp(bf16) = X @ W  via bf16 MFMA (f32 accumulate).
// ---------------------------------------------------------------------------
__global__ __launch_bounds__(256) void gemm_mfma(const float* __restrict__ X,
                                                 const bf16x8* __restrict__ Wp,
                                                 __bf16* __restrict__ Xpb) {
    __shared__ __bf16 As[BM][D];   // 32 KB, XOR-swizzled in 16B chunks
    const int tid = threadIdx.x;
    const int r0  = blockIdx.x * BM;

    #pragma unroll
    for (int i = 0; i < 8; ++i) {
        const int g   = tid + i * 256;
        const int row = g >> 5;
        const int cc  = g & 31;
        const int gr  = min(r0 + row, N_NODES - 1);
        const float4 f0 = reinterpret_cast<const float4*>(X)[(size_t)gr * 64 + cc * 2 + 0];
        const float4 f1 = reinterpret_cast<const float4*>(X)[(size_t)gr * 64 + cc * 2 + 1];
        bf16x8 v;
        v[0] = (__bf16)f0.x; v[1] = (__bf16)f0.y; v[2] = (__bf16)f0.z; v[3] = (__bf16)f0.w;
        v[4] = (__bf16)f1.x; v[5] = (__bf16)f1.y; v[6] = (__bf16)f1.z; v[7] = (__bf16)f1.w;
        const int sw = cc ^ (row & 7);
        *reinterpret_cast<bf16x8*>(&As[row][sw * 8]) = v;
    }
    __syncthreads();

    const int w = tid >> 6;
    const int l = tid & 63;

    f32x4 acc[4][4];
    #pragma unroll
    for (int mt = 0; mt < 4; ++mt)
        #pragma unroll
        for (int nt = 0; nt < 4; ++nt) acc[mt][nt] = (f32x4){0.f, 0.f, 0.f, 0.f};

    #pragma unroll
    for (int ks = 0; ks < 8; ++ks) {
        bf16x8 a[4];
        #pragma unroll
        for (int mt = 0; mt < 4; ++mt) {
            const int row = mt * 16 + (l & 15);
            const int ch  = (ks * 4 + (l >> 4)) ^ (row & 7);
            a[mt] = *reinterpret_cast<const bf16x8*>(&As[row][ch * 8]);
        }
        #pragma unroll
        for (int nt = 0; nt < 4; ++nt) {
            const bf16x8 b = Wp[(ks * 16 + w * 4 + nt) * 64 + l];
            #pragma unroll
            for (int mt = 0; mt < 4; ++mt)
                acc[mt][nt] = __builtin_amdgcn_mfma_f32_16x16x32_bf16(a[mt], b, acc[mt][nt], 0, 0, 0);
        }
    }

    #pragma unroll
    for (int mt = 0; mt < 4; ++mt) {
        const int rbase = r0 + mt * 16 + (l >> 4) * 4;
        #pragma unroll
        for (int reg = 0; reg < 4; ++reg) {
            const int r = rbase + reg;
            if (r >= N_NODES) continue;
            #pragma unroll
            for (int nt = 0; nt < 4; ++nt)
                Xpb[(size_t)r * D + w * 64 + nt * 16 + (l & 15)] = (__bf16)acc[mt][nt][reg];
        }
    }
}

// ---------------------------------------------------------------------------
// CSR build, bucket-sorted (no global per-key histogram, no scattered fill)
// ---------------------------------------------------------------------------
// 2a: per-block LDS histogram over 98 buckets per direction
__global__ __launch_bounds__(256) void bucket_hist(const int* __restrict__ ei,
                                                   const int* __restrict__ ni,
                                                   int* __restrict__ gcnt_e,
                                                   int* __restrict__ gcnt_v) {
    __shared__ int eh[128], vh[128];
    const int t = threadIdx.x;
    if (t < 128) { eh[t] = 0; vh[t] = 0; }
    __syncthreads();
    const int start = blockIdx.x * ENT;
    #pragma unroll
    for (int k = 0; k < ENT / 256; ++k) {
        const int g = start + k * 256 + t;
        if (g < NNZ) {
            atomicAdd(&eh[ei[g] >> ESH], 1);
            atomicAdd(&vh[ni[g] >> VSH], 1);
        }
    }
    __syncthreads();
    if (t < NB) {
        if (eh[t]) atomicAdd(&gcnt_e[t], eh[t]);
        if (vh[t]) atomicAdd(&gcnt_v[t], vh[t]);
    }
}

// 2b: single block — scan bucket counts into bases, init pass-A cursors,
//     set CSR offset sentinels.
__global__ __launch_bounds__(256) void bucket_scan(const int* __restrict__ gcnt_e,
                                                   const int* __restrict__ gcnt_v,
                                                   int* __restrict__ gbase_e,
                                                   int* __restrict__ gbase_v,
                                                   int* __restrict__ ecur,
                                                   int* __restrict__ vcur,
                                                   int* __restrict__ eoff,
                                                   int* __restrict__ voff) {
    __shared__ int s[256];
    const int t = threadIdx.x;
    int v = (t < NB) ? gcnt_e[t] : 0;
    s[t] = v; __syncthreads();
    #pragma unroll
    for (int d = 1; d < 256; d <<= 1) { int x = (t >= d) ? s[t - d] : 0; __syncthreads(); s[t] += x; __syncthreads(); }
    if (t < NB) { const int b = s[t] - v; gbase_e[t] = b; ecur[t] = b; }
    __syncthreads();
    int v2 = (t < NB) ? gcnt_v[t] : 0;
    s[t] = v2; __syncthreads();
    #pragma unroll
    for (int d = 1; d < 256; d <<= 1) { int x = (t >= d) ? s[t - d] : 0; __syncthreads(); s[t] += x; __syncthreads(); }
    if (t < NB) { const int b = s[t] - v2; gbase_v[t] = b; vcur[t] = b; }
    if (t == 0) {
        gbase_e[NB] = NNZ; gbase_v[NB] = NNZ;
        eoff[N_EDGES] = NNZ; voff[N_NODES] = NNZ;
    }
}

// 2c: multisplit — partition (key,payload) pairs into bucket regions with
//     block-aggregated contiguous runs (coalesced writes).
__global__ __launch_bounds__(256) void multisplit(const int* __restrict__ ei,
                                                  const int* __restrict__ ni,
                                                  int* __restrict__ egcur,
                                                  int* __restrict__ vgcur,
                                                  uint2* __restrict__ etmp,
                                                  uint2* __restrict__ vtmp) {
    __shared__ int eh[128], vh[128], eb[128], vb[128];
    const int t = threadIdx.x;
    if (t < 128) { eh[t] = 0; vh[t] = 0; }
    __syncthreads();
    const int start = blockIdx.x * ENT;
    int ek[ENT / 256], nk[ENT / 256];
    #pragma unroll
    for (int k = 0; k < ENT / 256; ++k) {
        const int g = start + k * 256 + t;
        if (g < NNZ) {
            ek[k] = ei[g]; nk[k] = ni[g];
            atomicAdd(&eh[ek[k] >> ESH], 1);
            atomicAdd(&vh[nk[k] >> VSH], 1);
        } else { ek[k] = -1; nk[k] = -1; }
    }
    __syncthreads();
    if (t < NB) {
        eb[t] = eh[t] ? atomicAdd(&egcur[t], eh[t]) : 0;
        vb[t] = vh[t] ? atomicAdd(&vgcur[t], vh[t]) : 0;
    }
    __syncthreads();
    if (t < 128) { eh[t] = 0; vh[t] = 0; }
    __syncthreads();
    #pragma unroll
    for (int k = 0; k < ENT / 256; ++k) {
        if (ek[k] >= 0) {
            int b = ek[k] >> ESH;
            int r = atomicAdd(&eh[b], 1);
            etmp[eb[b] + r] = make_uint2((unsigned)ek[k], (unsigned)nk[k]);
            b = nk[k] >> VSH;
            r = atomicAdd(&vh[b], 1);
            vtmp[vb[b] + r] = make_uint2((unsigned)nk[k], (unsigned)ek[k]);
        }
    }
}

// 2d: per-bucket block — per-key count + LDS scan -> CSR offsets, then rank
//     entries into final src positions (writes confined to one 32 KB region).
__global__ __launch_bounds__(256) void build_csr(const uint2* __restrict__ etmp,
                                                 const uint2* __restrict__ vtmp,
                                                 const int* __restrict__ gbase_e,
                                                 const int* __restrict__ gbase_v,
                                                 int* __restrict__ eoff,
                                                 int* __restrict__ voff,
                                                 int* __restrict__ esrc,
                                                 int* __restrict__ vsrc) {
    __shared__ int cnt[1024];
    __shared__ int s[256];
    const bool is_e = blockIdx.x < NB;
    const int b = is_e ? blockIdx.x : blockIdx.x - NB;
    const uint2* tmp = is_e ? etmp : vtmp;
    const int* gbase = is_e ? gbase_e : gbase_v;
    int* off = is_e ? eoff : voff;
    int* src = is_e ? esrc : vsrc;
    const int sh    = is_e ? ESH : VSH;
    const int klo   = b << sh;
    const int nkeys = is_e ? N_EDGES : N_NODES;
    const int nk    = min(1 << sh, nkeys - klo);
    const int base = gbase[b], end = gbase[b + 1];
    const int t = threadIdx.x;

    #pragma unroll
    for (int q = 0; q < 4; ++q) cnt[t * 4 + q] = 0;
    __syncthreads();
    for (int i = base + t; i < end; i += 256)
        atomicAdd(&cnt[(int)tmp[i].x - klo], 1);
    __syncthreads();
    // exclusive scan of cnt[0..1024)
    int v[4]; int ts = 0;
    #pragma unroll
    for (int q = 0; q < 4; ++q) { v[q] = cnt[t * 4 + q]; ts += v[q]; }
    s[t] = ts; __syncthreads();
    #pragma unroll
    for (int d = 1; d < 256; d <<= 1) { int x = (t >= d) ? s[t - d] : 0; __syncthreads(); s[t] += x; __syncthreads(); }
    int run = s[t] - ts;
    #pragma unroll
    for (int q = 0; q < 4; ++q) { cnt[t * 4 + q] = run; run += v[q]; }
    __syncthreads();
    // write CSR offsets (coalesced)
    #pragma unroll
    for (int q = 0; q < 4; ++q) {
        const int j = t * 4 + q;
        if (j < nk) off[klo + j] = base + cnt[j];
    }
    __syncthreads();
    // rank entries; cnt[] doubles as per-key cursor (starts at local excl prefix)
    for (int i = base + t; i < end; i += 256) {
        const uint2 pr = tmp[i];
        const int p = atomicAdd(&cnt[(int)pr.x - klo], 1);
        src[base + p] = (int)pr.y;
    }
}

// ---------------------------------------------------------------------------
// Stage 1: Xe[e] = degE[e] * sum_{j in edge e} Xp[esrc[j]]   (wave per edge)
// ---------------------------------------------------------------------------
__global__ __launch_bounds__(256) void edge_gather(
        const __bf16* __restrict__ Xpb, const int* __restrict__ eoff,
        const int* __restrict__ esrc, const float* __restrict__ degE,
        __bf16* __restrict__ Xeb) {
    const int e = (blockIdx.x * 256 + threadIdx.x) >> 6;
    const int lane = threadIdx.x & 63;
    if (e >= N_EDGES) return;
    const int beg = eoff[e], end = eoff[e + 1];
    float a0 = 0.f, a1 = 0.f, a2 = 0.f, a3 = 0.f;
    const unsigned short* Xu = reinterpret_cast<const unsigned short*>(Xpb);
    int j = beg;
    for (; j + 1 < end; j += 2) {
        const int n0 = esrc[j];
        const int n1 = esrc[j + 1];
        const ushort4 u0 = *reinterpret_cast<const ushort4*>(Xu + (size_t)n0 * D + lane * 4);
        const ushort4 u1 = *reinterpret_cast<const ushort4*>(Xu + (size_t)n1 * D + lane * 4);
        a0 += bf2f(u0.x) + bf2f(u1.x);
        a1 += bf2f(u0.y) + bf2f(u1.y);
        a2 += bf2f(u0.z) + bf2f(u1.z);
        a3 += bf2f(u0.w) + bf2f(u1.w);
    }
    if (j < end) {
        const int n0 = esrc[j];
        const ushort4 u0 = *reinterpret_cast<const ushort4*>(Xu + (size_t)n0 * D + lane * 4);
        a0 += bf2f(u0.x); a1 += bf2f(u0.y); a2 += bf2f(u0.z); a3 += bf2f(u0.w);
    }
    const float sc = degE[e];
    bf16x4 o;
    o[0] = (__bf16)(a0 * sc); o[1] = (__bf16)(a1 * sc);
    o[2] = (__bf16)(a2 * sc); o[3] = (__bf16)(a3 * sc);
    *reinterpret_cast<bf16x4*>(Xeb + (size_t)e * D + lane * 4) = o;
}

// ---------------------------------------------------------------------------
// Stage 2 (fused finalize):
//   out[n] = (1+eps)*Xp[n] + degV[n] * sum_{j in node n} Xe[vsrc[j]]
// ---------------------------------------------------------------------------
__global__ __launch_bounds__(256) void node_gather(
        const __bf16* __restrict__ Xpb, const __bf16* __restrict__ Xeb,
        const int* __restrict__ voff, const int* __restrict__ vsrc,
        const float* __restrict__ degV, const float* __restrict__ eps,
        float* __restrict__ out) {
    const int nd = (blockIdx.x * 256 + threadIdx.x) >> 6;
    const int lane = threadIdx.x & 63;
    if (nd >= N_NODES) return;
    const int beg = voff[nd], end = voff[nd + 1];
    const unsigned short* Xu = reinterpret_cast<const unsigned short*>(Xeb);
    const ushort4 up = *reinterpret_cast<const ushort4*>(
        reinterpret_cast<const unsigned short*>(Xpb) + (size_t)nd * D + lane * 4);
    float a0 = 0.f, a1 = 0.f, a2 = 0.f, a3 = 0.f;
    int j = beg;
    for (; j + 1 < end; j += 2) {
        const int e0 = vsrc[j];
        const int e1 = vsrc[j + 1];
        const ushort4 u0 = *reinterpret_cast<const ushort4*>(Xu + (size_t)e0 * D + lane * 4);
        const ushort4 u1 = *reinterpret_cast<const ushort4*>(Xu + (size_t)e1 * D + lane * 4);
        a0 += bf2f(u0.x) + bf2f(u1.x);
        a1 += bf2f(u0.y) + bf2f(u1.y);
        a2 += bf2f(u0.z) + bf2f(u1.z);
        a3 += bf2f(u0.w) + bf2f(u1.w);
    }
    if (j < end) {
        const int e0 = vsrc[j];
        const ushort4 u0 = *reinterpret_cast<const ushort4*>(Xu + (size_t)e0 * D + lane * 4);
        a0 += bf2f(u0.x); a1 += bf2f(u0.y); a2 += bf2f(u0.z); a3 += bf2f(u0.w);
    }
    const float dv = degV[nd];
    const float ep = 1.f + eps[0];
    float4 o;
    o.x = ep * bf2f(up.x) + dv * a0;
    o.y = ep * bf2f(up.y) + dv * a1;
    o.z = ep * bf2f(up.z) + dv * a2;
    o.w = ep * bf2f(up.w) + dv * a3;
    *reinterpret_cast<float4*>(out + (size_t)nd * D + lane * 4) = o;
}

// ---------------------------------------------------------------------------
extern "C" void kernel_launch(void* const* d_in, const int* in_sizes, int n_in,
                              void* d_out, int out_size, void* d_ws, size_t ws_size,
                              hipStream_t stream) {
    const float* X        = (const float*)d_in[0];
    const float* W        = (const float*)d_in[1];
    const float* eps      = (const float*)d_in[2];
    const float* degE     = (const float*)d_in[3];
    const float* degV     = (const float*)d_in[4];
    const int*   node_idx = (const int*)d_in[5];
    const int*   edge_idx = (const int*)d_in[6];

    float* out = (float*)d_out;

    // ---- workspace layout (8B-aligned blocks first) ----
    char* p = (char*)d_ws;
    __bf16* Xpb = (__bf16*)p; p += (size_t)N_NODES * D * sizeof(__bf16);  // 51.2 MB
    __bf16* Xeb = (__bf16*)p; p += (size_t)N_EDGES * D * sizeof(__bf16);  // 25.6 MB
    bf16x8* Wp  = (bf16x8*)p; p += (size_t)8 * 16 * 64 * sizeof(bf16x8);  // 128 KB
    uint2* etmp = (uint2*)p;  p += (size_t)NNZ * sizeof(uint2);           // 6.4 MB
    uint2* vtmp = (uint2*)p;  p += (size_t)NNZ * sizeof(uint2);           // 6.4 MB
    int* esrc   = (int*)p;    p += (size_t)NNZ * sizeof(int);
    int* vsrc   = (int*)p;    p += (size_t)NNZ * sizeof(int);
    int* eoff   = (int*)p;    p += ((size_t)N_EDGES + 8) * sizeof(int);
    int* voff   = (int*)p;    p += ((size_t)N_NODES + 8) * sizeof(int);
    int* gcnt_e = (int*)p;    p += 128 * sizeof(int);   // gcnt_e+gcnt_v contiguous
    int* gcnt_v = (int*)p;    p += 128 * sizeof(int);
    int* gbase_e = (int*)p;   p += 128 * sizeof(int);
    int* gbase_v = (int*)p;   p += 128 * sizeof(int);
    int* ecur   = (int*)p;    p += 128 * sizeof(int);
    int* vcur   = (int*)p;    p += 128 * sizeof(int);

    // 1) GEMM (bf16 MFMA)
    pack_W<<<32, 256, 0, stream>>>(W, Wp);
    gemm_mfma<<<(N_NODES + BM - 1) / BM, 256, 0, stream>>>(X, Wp, Xpb);

    // 2) CSR build via bucket sort
    hipMemsetAsync(gcnt_e, 0, 256 * sizeof(int), stream);
    bucket_hist<<<MS_BLOCKS, 256, 0, stream>>>(edge_idx, node_idx, gcnt_e, gcnt_v);
    bucket_scan<<<1, 256, 0, stream>>>(gcnt_e, gcnt_v, gbase_e, gbase_v,
                                       ecur, vcur, eoff, voff);
    multisplit<<<MS_BLOCKS, 256, 0, stream>>>(edge_idx, node_idx, ecur, vcur,
                                              etmp, vtmp);
    build_csr<<<2 * NB, 256, 0, stream>>>(etmp, vtmp, gbase_e, gbase_v,
                                          eoff, voff, esrc, vsrc);

    // 3) nodes -> edges (gather, fused degE)
    edge_gather<<<(N_EDGES * 64 + 255) / 256, 256, 0, stream>>>(
        Xpb, eoff, esrc, degE, Xeb);

    // 4) edges -> nodes (gather, fused degV + (1+eps)*Xp residual)
    node_gather<<<(N_NODES * 64 + 255) / 256, 256, 0, stream>>>(
        Xpb, Xeb, voff, vsrc, degV, eps, out);
}

// Round 6
// 247.087 us; speedup vs baseline: 22.8370x; 1.1153x over previous
//
#include <hip/hip_runtime.h>

#define N_NODES 100000
#define N_EDGES 50000
#define NNZ     800000
#define D       256

#define BM 64            // gemm rows per block

// bucket-sort CSR build
#define NB   98          // buckets per direction
#define ESH  9           // edge bucket shift: 512 keys/bucket (98*512 >= 50000)
#define VSH  10          // node bucket shift: 1024 keys/bucket (98*1024 >= 100000)
#define ENT  4096        // entries per multisplit/hist block
#define MS_BLOCKS ((NNZ + ENT - 1) / ENT)   // 196

typedef __bf16 bf16x8 __attribute__((ext_vector_type(8)));
typedef float  f32x4  __attribute__((ext_vector_type(4)));

// accumulate 8 bf16 (packed in uint4) into 8 f32 accumulators
__device__ __forceinline__ void acc8(float* a, const uint4 u) {
    union { unsigned int i; float f; } t;
    t.i = u.x << 16;         a[0] += t.f;
    t.i = u.x & 0xffff0000u; a[1] += t.f;
    t.i = u.y << 16;         a[2] += t.f;
    t.i = u.y & 0xffff0000u; a[3] += t.f;
    t.i = u.z << 16;         a[4] += t.f;
    t.i = u.z & 0xffff0000u; a[5] += t.f;
    t.i = u.w << 16;         a[6] += t.f;
    t.i = u.w & 0xffff0000u; a[7] += t.f;
}

__device__ __forceinline__ void unpack8(float* a, const uint4 u) {
    union { unsigned int i; float f; } t;
    t.i = u.x << 16;         a[0] = t.f;
    t.i = u.x & 0xffff0000u; a[1] = t.f;
    t.i = u.y << 16;         a[2] = t.f;
    t.i = u.y & 0xffff0000u; a[3] = t.f;
    t.i = u.z << 16;         a[4] = t.f;
    t.i = u.z & 0xffff0000u; a[5] = t.f;
    t.i = u.w << 16;         a[6] = t.f;
    t.i = u.w & 0xffff0000u; a[7] = t.f;
}

// ---------------------------------------------------------------------------
// Kernel 0: pack W (f32 [256][256]) into bf16 MFMA b-fragment order.
// ---------------------------------------------------------------------------
__global__ __launch_bounds__(256) void pack_W(const float* __restrict__ W,
                                              bf16x8* __restrict__ Wp) {
    const int t = blockIdx.x * 256 + threadIdx.x;   // 8192 total
    if (t >= 8 * 16 * 64) return;
    const int ks  = t >> 10;
    const int n16 = (t >> 6) & 15;
    const int l   = t & 63;
    const int kb  = ks * 32 + (l >> 4) * 8;
    const int col = n16 * 16 + (l & 15);
    bf16x8 v;
    #pragma unroll
    for (int j = 0; j < 8; ++j) v[j] = (__bf16)W[(size_t)(kb + j) * D + col];
    Wp[t] = v;
}

// ---------------------------------------------------------------------------
// Kernel 1: Xp(bf16) = X @ W  via bf16 MFMA (f32 accumulate).
// ---------------------------------------------------------------------------
__global__ __launch_bounds__(256) void gemm_mfma(const float* __restrict__ X,
                                                 const bf16x8* __restrict__ Wp,
                                                 __bf16* __restrict__ Xpb) {
    __shared__ __bf16 As[BM][D];   // 32 KB, XOR-swizzled in 16B chunks
    const int tid = threadIdx.x;
    const int r0  = blockIdx.x * BM;

    #pragma unroll
    for (int i = 0; i < 8; ++i) {
        const int g   = tid + i * 256;
        const int row = g >> 5;
        const int cc  = g & 31;
        const int gr  = min(r0 + row, N_NODES - 1);
        const float4 f0 = reinterpret_cast<const float4*>(X)[(size_t)gr * 64 + cc * 2 + 0];
        const float4 f1 = reinterpret_cast<const float4*>(X)[(size_t)gr * 64 + cc * 2 + 1];
        bf16x8 v;
        v[0] = (__bf16)f0.x; v[1] = (__bf16)f0.y; v[2] = (__bf16)f0.z; v[3] = (__bf16)f0.w;
        v[4] = (__bf16)f1.x; v[5] = (__bf16)f1.y; v[6] = (__bf16)f1.z; v[7] = (__bf16)f1.w;
        const int sw = cc ^ (row & 7);
        *reinterpret_cast<bf16x8*>(&As[row][sw * 8]) = v;
    }
    __syncthreads();

    const int w = tid >> 6;
    const int l = tid & 63;

    f32x4 acc[4][4];
    #pragma unroll
    for (int mt = 0; mt < 4; ++mt)
        #pragma unroll
        for (int nt = 0; nt < 4; ++nt) acc[mt][nt] = (f32x4){0.f, 0.f, 0.f, 0.f};

    #pragma unroll
    for (int ks = 0; ks < 8; ++ks) {
        bf16x8 a[4];
        #pragma unroll
        for (int mt = 0; mt < 4; ++mt) {
            const int row = mt * 16 + (l & 15);
            const int ch  = (ks * 4 + (l >> 4)) ^ (row & 7);
            a[mt] = *reinterpret_cast<const bf16x8*>(&As[row][ch * 8]);
        }
        #pragma unroll
        for (int nt = 0; nt < 4; ++nt) {
            const bf16x8 b = Wp[(ks * 16 + w * 4 + nt) * 64 + l];
            #pragma unroll
            for (int mt = 0; mt < 4; ++mt)
                acc[mt][nt] = __builtin_amdgcn_mfma_f32_16x16x32_bf16(a[mt], b, acc[mt][nt], 0, 0, 0);
        }
    }

    #pragma unroll
    for (int mt = 0; mt < 4; ++mt) {
        const int rbase = r0 + mt * 16 + (l >> 4) * 4;
        #pragma unroll
        for (int reg = 0; reg < 4; ++reg) {
            const int r = rbase + reg;
            if (r >= N_NODES) continue;
            #pragma unroll
            for (int nt = 0; nt < 4; ++nt)
                Xpb[(size_t)r * D + w * 64 + nt * 16 + (l & 15)] = (__bf16)acc[mt][nt][reg];
        }
    }
}

// ---------------------------------------------------------------------------
// CSR build, bucket-sorted (no global per-key histogram, no scattered fill)
// ---------------------------------------------------------------------------
__global__ __launch_bounds__(256) void bucket_hist(const int* __restrict__ ei,
                                                   const int* __restrict__ ni,
                                                   int* __restrict__ gcnt_e,
                                                   int* __restrict__ gcnt_v) {
    __shared__ int eh[128], vh[128];
    const int t = threadIdx.x;
    if (t < 128) { eh[t] = 0; vh[t] = 0; }
    __syncthreads();
    const int start = blockIdx.x * ENT;
    #pragma unroll
    for (int k = 0; k < ENT / 256; ++k) {
        const int g = start + k * 256 + t;
        if (g < NNZ) {
            atomicAdd(&eh[ei[g] >> ESH], 1);
            atomicAdd(&vh[ni[g] >> VSH], 1);
        }
    }
    __syncthreads();
    if (t < NB) {
        if (eh[t]) atomicAdd(&gcnt_e[t], eh[t]);
        if (vh[t]) atomicAdd(&gcnt_v[t], vh[t]);
    }
}

__global__ __launch_bounds__(256) void bucket_scan(const int* __restrict__ gcnt_e,
                                                   const int* __restrict__ gcnt_v,
                                                   int* __restrict__ gbase_e,
                                                   int* __restrict__ gbase_v,
                                                   int* __restrict__ ecur,
                                                   int* __restrict__ vcur,
                                                   int* __restrict__ eoff,
                                                   int* __restrict__ voff) {
    __shared__ int s[256];
    const int t = threadIdx.x;
    int v = (t < NB) ? gcnt_e[t] : 0;
    s[t] = v; __syncthreads();
    #pragma unroll
    for (int d = 1; d < 256; d <<= 1) { int x = (t >= d) ? s[t - d] : 0; __syncthreads(); s[t] += x; __syncthreads(); }
    if (t < NB) { const int b = s[t] - v; gbase_e[t] = b; ecur[t] = b; }
    __syncthreads();
    int v2 = (t < NB) ? gcnt_v[t] : 0;
    s[t] = v2; __syncthreads();
    #pragma unroll
    for (int d = 1; d < 256; d <<= 1) { int x = (t >= d) ? s[t - d] : 0; __syncthreads(); s[t] += x; __syncthreads(); }
    if (t < NB) { const int b = s[t] - v2; gbase_v[t] = b; vcur[t] = b; }
    if (t == 0) {
        gbase_e[NB] = NNZ; gbase_v[NB] = NNZ;
        eoff[N_EDGES] = NNZ; voff[N_NODES] = NNZ;
    }
}

__global__ __launch_bounds__(256) void multisplit(const int* __restrict__ ei,
                                                  const int* __restrict__ ni,
                                                  int* __restrict__ egcur,
                                                  int* __restrict__ vgcur,
                                                  uint2* __restrict__ etmp,
                                                  uint2* __restrict__ vtmp) {
    __shared__ int eh[128], vh[128], eb[128], vb[128];
    const int t = threadIdx.x;
    if (t < 128) { eh[t] = 0; vh[t] = 0; }
    __syncthreads();
    const int start = blockIdx.x * ENT;
    int ek[ENT / 256], nk[ENT / 256];
    #pragma unroll
    for (int k = 0; k < ENT / 256; ++k) {
        const int g = start + k * 256 + t;
        if (g < NNZ) {
            ek[k] = ei[g]; nk[k] = ni[g];
            atomicAdd(&eh[ek[k] >> ESH], 1);
            atomicAdd(&vh[nk[k] >> VSH], 1);
        } else { ek[k] = -1; nk[k] = -1; }
    }
    __syncthreads();
    if (t < NB) {
        eb[t] = eh[t] ? atomicAdd(&egcur[t], eh[t]) : 0;
        vb[t] = vh[t] ? atomicAdd(&vgcur[t], vh[t]) : 0;
    }
    __syncthreads();
    if (t < 128) { eh[t] = 0; vh[t] = 0; }
    __syncthreads();
    #pragma unroll
    for (int k = 0; k < ENT / 256; ++k) {
        if (ek[k] >= 0) {
            int b = ek[k] >> ESH;
            int r = atomicAdd(&eh[b], 1);
            etmp[eb[b] + r] = make_uint2((unsigned)ek[k], (unsigned)nk[k]);
            b = nk[k] >> VSH;
            r = atomicAdd(&vh[b], 1);
            vtmp[vb[b] + r] = make_uint2((unsigned)nk[k], (unsigned)ek[k]);
        }
    }
}

__global__ __launch_bounds__(256) void build_csr(const uint2* __restrict__ etmp,
                                                 const uint2* __restrict__ vtmp,
                                                 const int* __restrict__ gbase_e,
                                                 const int* __restrict__ gbase_v,
                                                 int* __restrict__ eoff,
                                                 int* __restrict__ voff,
                                                 int* __restrict__ esrc,
                                                 int* __restrict__ vsrc) {
    __shared__ int cnt[1024];
    __shared__ int s[256];
    const bool is_e = blockIdx.x < NB;
    const int b = is_e ? blockIdx.x : blockIdx.x - NB;
    const uint2* tmp = is_e ? etmp : vtmp;
    const int* gbase = is_e ? gbase_e : gbase_v;
    int* off = is_e ? eoff : voff;
    int* src = is_e ? esrc : vsrc;
    const int sh    = is_e ? ESH : VSH;
    const int klo   = b << sh;
    const int nkeys = is_e ? N_EDGES : N_NODES;
    const int nk    = min(1 << sh, nkeys - klo);
    const int base = gbase[b], end = gbase[b + 1];
    const int t = threadIdx.x;

    #pragma unroll
    for (int q = 0; q < 4; ++q) cnt[t * 4 + q] = 0;
    __syncthreads();
    for (int i = base + t; i < end; i += 256)
        atomicAdd(&cnt[(int)tmp[i].x - klo], 1);
    __syncthreads();
    int v[4]; int ts = 0;
    #pragma unroll
    for (int q = 0; q < 4; ++q) { v[q] = cnt[t * 4 + q]; ts += v[q]; }
    s[t] = ts; __syncthreads();
    #pragma unroll
    for (int d = 1; d < 256; d <<= 1) { int x = (t >= d) ? s[t - d] : 0; __syncthreads(); s[t] += x; __syncthreads(); }
    int run = s[t] - ts;
    #pragma unroll
    for (int q = 0; q < 4; ++q) { cnt[t * 4 + q] = run; run += v[q]; }
    __syncthreads();
    #pragma unroll
    for (int q = 0; q < 4; ++q) {
        const int j = t * 4 + q;
        if (j < nk) off[klo + j] = base + cnt[j];
    }
    __syncthreads();
    for (int i = base + t; i < end; i += 256) {
        const uint2 pr = tmp[i];
        const int p = atomicAdd(&cnt[(int)pr.x - klo], 1);
        src[base + p] = (int)pr.y;
    }
}

// ---------------------------------------------------------------------------
// Stage 1: Xe[e] = degE[e] * sum_{j in edge e} Xp[esrc[j]]
// Wave per edge; indices preloaded per 64-chunk + __shfl broadcast;
// two 32-lane halves each cover a full row at 16 B/lane (uint4).
// ---------------------------------------------------------------------------
__global__ __launch_bounds__(256) void edge_gather(
        const __bf16* __restrict__ Xpb, const int* __restrict__ eoff,
        const int* __restrict__ esrc, const float* __restrict__ degE,
        __bf16* __restrict__ Xeb) {
    const int e = (blockIdx.x * 256 + threadIdx.x) >> 6;
    if (e >= N_EDGES) return;
    const int lane = threadIdx.x & 63;
    const int half = lane >> 5;
    const int c0   = (lane & 31) * 8;
    const int beg = eoff[e], end = eoff[e + 1];
    const unsigned short* Xu = reinterpret_cast<const unsigned short*>(Xpb);

    float acc[8];
    #pragma unroll
    for (int q = 0; q < 8; ++q) acc[q] = 0.f;

    for (int cb = beg; cb < end; cb += 64) {
        const int cnt = min(64, end - cb);
        const int my = (lane < cnt) ? esrc[cb + lane] : 0;   // one coalesced load
        int jj = 0;
        for (; jj + 4 <= cnt; jj += 4) {
            const int r0 = __shfl(my, jj + half);
            const int r1 = __shfl(my, jj + 2 + half);
            const uint4 u0 = *reinterpret_cast<const uint4*>(Xu + (size_t)r0 * D + c0);
            const uint4 u1 = *reinterpret_cast<const uint4*>(Xu + (size_t)r1 * D + c0);
            acc8(acc, u0);
            acc8(acc, u1);
        }
        for (; jj < cnt; jj += 2) {
            const int rr = jj + half;
            const int r = __shfl(my, rr < cnt ? rr : cnt - 1);
            if (rr < cnt) {
                const uint4 u = *reinterpret_cast<const uint4*>(Xu + (size_t)r * D + c0);
                acc8(acc, u);
            }
        }
    }

    #pragma unroll
    for (int q = 0; q < 8; ++q) acc[q] += __shfl_xor(acc[q], 32);

    if (half == 0) {
        const float s = degE[e];
        bf16x8 v;
        #pragma unroll
        for (int q = 0; q < 8; ++q) v[q] = (__bf16)(acc[q] * s);
        *reinterpret_cast<bf16x8*>(Xeb + (size_t)e * D + c0) = v;
    }
}

// ---------------------------------------------------------------------------
// Stage 2 (fused finalize):
//   out[n] = (1+eps)*Xp[n] + degV[n] * sum_{j in node n} Xe[vsrc[j]]
// ---------------------------------------------------------------------------
__global__ __launch_bounds__(256) void node_gather(
        const __bf16* __restrict__ Xpb, const __bf16* __restrict__ Xeb,
        const int* __restrict__ voff, const int* __restrict__ vsrc,
        const float* __restrict__ degV, const float* __restrict__ eps,
        float* __restrict__ out) {
    const int nd = (blockIdx.x * 256 + threadIdx.x) >> 6;
    if (nd >= N_NODES) return;
    const int lane = threadIdx.x & 63;
    const int half = lane >> 5;
    const int c0   = (lane & 31) * 8;
    const int beg = voff[nd], end = voff[nd + 1];
    const unsigned short* Xu = reinterpret_cast<const unsigned short*>(Xeb);

    // residual row chunk (issued early, independent of gather chain)
    const uint4 up = *reinterpret_cast<const uint4*>(
        reinterpret_cast<const unsigned short*>(Xpb) + (size_t)nd * D + c0);

    float acc[8];
    #pragma unroll
    for (int q = 0; q < 8; ++q) acc[q] = 0.f;

    for (int cb = beg; cb < end; cb += 64) {
        const int cnt = min(64, end - cb);
        const int my = (lane < cnt) ? vsrc[cb + lane] : 0;
        int jj = 0;
        for (; jj + 4 <= cnt; jj += 4) {
            const int r0 = __shfl(my, jj + half);
            const int r1 = __shfl(my, jj + 2 + half);
            const uint4 u0 = *reinterpret_cast<const uint4*>(Xu + (size_t)r0 * D + c0);
            const uint4 u1 = *reinterpret_cast<const uint4*>(Xu + (size_t)r1 * D + c0);
            acc8(acc, u0);
            acc8(acc, u1);
        }
        for (; jj < cnt; jj += 2) {
            const int rr = jj + half;
            const int r = __shfl(my, rr < cnt ? rr : cnt - 1);
            if (rr < cnt) {
                const uint4 u = *reinterpret_cast<const uint4*>(Xu + (size_t)r * D + c0);
                acc8(acc, u);
            }
        }
    }

    #pragma unroll
    for (int q = 0; q < 8; ++q) acc[q] += __shfl_xor(acc[q], 32);

    if (half == 0) {
        const float dv = degV[nd];
        const float ep = 1.f + eps[0];
        float xr[8];
        unpack8(xr, up);
        float4 o0, o1;
        o0.x = ep * xr[0] + dv * acc[0];
        o0.y = ep * xr[1] + dv * acc[1];
        o0.z = ep * xr[2] + dv * acc[2];
        o0.w = ep * xr[3] + dv * acc[3];
        o1.x = ep * xr[4] + dv * acc[4];
        o1.y = ep * xr[5] + dv * acc[5];
        o1.z = ep * xr[6] + dv * acc[6];
        o1.w = ep * xr[7] + dv * acc[7];
        float* op = out + (size_t)nd * D + c0;
        *reinterpret_cast<float4*>(op)     = o0;
        *reinterpret_cast<float4*>(op + 4) = o1;
    }
}

// ---------------------------------------------------------------------------
extern "C" void kernel_launch(void* const* d_in, const int* in_sizes, int n_in,
                              void* d_out, int out_size, void* d_ws, size_t ws_size,
                              hipStream_t stream) {
    const float* X        = (const float*)d_in[0];
    const float* W        = (const float*)d_in[1];
    const float* eps      = (const float*)d_in[2];
    const float* degE     = (const float*)d_in[3];
    const float* degV     = (const float*)d_in[4];
    const int*   node_idx = (const int*)d_in[5];
    const int*   edge_idx = (const int*)d_in[6];

    float* out = (float*)d_out;

    // ---- workspace layout (8B-aligned blocks first) ----
    char* p = (char*)d_ws;
    __bf16* Xpb = (__bf16*)p; p += (size_t)N_NODES * D * sizeof(__bf16);  // 51.2 MB
    __bf16* Xeb = (__bf16*)p; p += (size_t)N_EDGES * D * sizeof(__bf16);  // 25.6 MB
    bf16x8* Wp  = (bf16x8*)p; p += (size_t)8 * 16 * 64 * sizeof(bf16x8);  // 128 KB
    uint2* etmp = (uint2*)p;  p += (size_t)NNZ * sizeof(uint2);           // 6.4 MB
    uint2* vtmp = (uint2*)p;  p += (size_t)NNZ * sizeof(uint2);           // 6.4 MB
    int* esrc   = (int*)p;    p += (size_t)NNZ * sizeof(int);
    int* vsrc   = (int*)p;    p += (size_t)NNZ * sizeof(int);
    int* eoff   = (int*)p;    p += ((size_t)N_EDGES + 8) * sizeof(int);
    int* voff   = (int*)p;    p += ((size_t)N_NODES + 8) * sizeof(int);
    int* gcnt_e = (int*)p;    p += 128 * sizeof(int);
    int* gcnt_v = (int*)p;    p += 128 * sizeof(int);
    int* gbase_e = (int*)p;   p += 128 * sizeof(int);
    int* gbase_v = (int*)p;   p += 128 * sizeof(int);
    int* ecur   = (int*)p;    p += 128 * sizeof(int);
    int* vcur   = (int*)p;    p += 128 * sizeof(int);

    // 1) GEMM (bf16 MFMA)
    pack_W<<<32, 256, 0, stream>>>(W, Wp);
    gemm_mfma<<<(N_NODES + BM - 1) / BM, 256, 0, stream>>>(X, Wp, Xpb);

    // 2) CSR build via bucket sort
    hipMemsetAsync(gcnt_e, 0, 256 * sizeof(int), stream);
    bucket_hist<<<MS_BLOCKS, 256, 0, stream>>>(edge_idx, node_idx, gcnt_e, gcnt_v);
    bucket_scan<<<1, 256, 0, stream>>>(gcnt_e, gcnt_v, gbase_e, gbase_v,
                                       ecur, vcur, eoff, voff);
    multisplit<<<MS_BLOCKS, 256, 0, stream>>>(edge_idx, node_idx, ecur, vcur,
                                              etmp, vtmp);
    build_csr<<<2 * NB, 256, 0, stream>>>(etmp, vtmp, gbase_e, gbase_v,
                                          eoff, voff, esrc, vsrc);

    // 3) nodes -> edges (gather, fused degE)
    edge_gather<<<(N_EDGES * 64 + 255) / 256, 256, 0, stream>>>(
        Xpb, eoff, esrc, degE, Xeb);

    // 4) edges -> nodes (gather, fused degV + (1+eps)*Xp residual)
    node_gather<<<(N_NODES * 64 + 255) / 256, 256, 0, stream>>>(
        Xpb, Xeb, voff, vsrc, degV, eps, out);
}